// Round 1
// baseline (89711.670 us; speedup 1.0000x reference)
//
#include <hip/hip_runtime.h>
#include <hip/hip_bf16.h>
#include <hip/hip_fp16.h>

// Problem constants
#define B_  256
#define T_  256
#define M_  512
#define P_  512

__device__ __forceinline__ float fast_tanh(float x) {
    // tanh(x) = 1 - 2/(exp(2x)+1); robust for all x (inf/0 handled by exp)
    float e2 = __expf(2.0f * x);
    return 1.0f - 2.0f * __frcp_rn(e2 + 1.0f);
}

__device__ __forceinline__ float fast_sigmoid(float x) {
    return __frcp_rn(1.0f + __expf(-x));
}

// ---------------------------------------------------------------------------
// init: copy d0, s0 into working state buffers
__global__ void init_state(const float* __restrict__ d0, const float* __restrict__ s0,
                           float* __restrict__ dbuf, float* __restrict__ sbuf) {
    int i = blockIdx.x * 256 + threadIdx.x;   // grid 512 x 256 = 131072
    dbuf[i] = d0[i];
    sbuf[i] = s0[i];
}

// ---------------------------------------------------------------------------
// UHh[r, n] = (half) sum_k H[r,k] * Ud[n,k]   r in [0,65536), n,k in [0,512)
__global__ __launch_bounds__(256) void uh_gemm(const float* __restrict__ H,
                                               const float* __restrict__ Ud,
                                               __half* __restrict__ UHh) {
    __shared__ float As[16][65];  // [k][row]
    __shared__ float Bs[16][65];  // [k][n]
    int tid = threadIdx.x;
    int tx = tid & 15;   // n dir
    int ty = tid >> 4;   // row dir
    int r0 = blockIdx.x * 64;
    int n0 = blockIdx.y * 64;
    int lr = tid >> 2;          // 0..63
    int lk = (tid & 3) * 4;     // 0,4,8,12

    float acc[4][4];
#pragma unroll
    for (int i = 0; i < 4; i++)
#pragma unroll
        for (int j = 0; j < 4; j++) acc[i][j] = 0.0f;

    for (int k0 = 0; k0 < 512; k0 += 16) {
        float4 a4 = *(const float4*)(H  + (size_t)(r0 + lr) * 512 + k0 + lk);
        float4 b4 = *(const float4*)(Ud + (size_t)(n0 + lr) * 512 + k0 + lk);
        As[lk + 0][lr] = a4.x; As[lk + 1][lr] = a4.y;
        As[lk + 2][lr] = a4.z; As[lk + 3][lr] = a4.w;
        Bs[lk + 0][lr] = b4.x; Bs[lk + 1][lr] = b4.y;
        Bs[lk + 2][lr] = b4.z; Bs[lk + 3][lr] = b4.w;
        __syncthreads();
#pragma unroll
        for (int kk = 0; kk < 16; kk++) {
            float a[4], b[4];
#pragma unroll
            for (int i = 0; i < 4; i++) a[i] = As[kk][ty + 16 * i];
#pragma unroll
            for (int j = 0; j < 4; j++) b[j] = Bs[kk][tx + 16 * j];
#pragma unroll
            for (int i = 0; i < 4; i++)
#pragma unroll
                for (int j = 0; j < 4; j++) acc[i][j] = fmaf(a[i], b[j], acc[i][j]);
        }
        __syncthreads();
    }
#pragma unroll
    for (int i = 0; i < 4; i++)
#pragma unroll
        for (int j = 0; j < 4; j++)
            UHh[(size_t)(r0 + ty + 16 * i) * 512 + (n0 + tx + 16 * j)] = __float2half(acc[i][j]);
}

// ---------------------------------------------------------------------------
// wq[b,n] = sum_j q[b,j] * Wd[n,j],  q = [d | s] (length 1024)
__global__ __launch_bounds__(512) void wq_kernel(const float* __restrict__ dcur,
                                                 const float* __restrict__ scur,
                                                 const float* __restrict__ Wd,
                                                 float* __restrict__ wq) {
    __shared__ float qs[16][1024];
    int tid = threadIdx.x;                // 512
    int b0 = blockIdx.x * 16;
    int n0 = blockIdx.y * 32;
    for (int idx = tid; idx < 16 * 1024; idx += 512) {
        int bb = idx >> 10, j = idx & 1023;
        qs[bb][j] = (j < 512) ? dcur[(size_t)(b0 + bb) * 512 + j]
                              : scur[(size_t)(b0 + bb) * 512 + (j - 512)];
    }
    __syncthreads();
    int bb = tid >> 5, nn = tid & 31;
    const float4* w4 = (const float4*)(Wd + (size_t)(n0 + nn) * 1024);
    const float4* q4 = (const float4*)(qs[bb]);
    float acc = 0.0f;
#pragma unroll 8
    for (int k = 0; k < 256; k++) {
        float4 a = q4[k], w = w4[k];
        acc = fmaf(a.x, w.x, acc); acc = fmaf(a.y, w.y, acc);
        acc = fmaf(a.z, w.z, acc); acc = fmaf(a.w, w.w, acc);
    }
    wq[(size_t)(b0 + bb) * 512 + n0 + nn] = acc;
}

// ---------------------------------------------------------------------------
// Per-b attention: e = tanh(wq + UH) @ v ; beta = softmax(e) ; c = beta @ H
// block = 512 threads (8 waves), grid = 256 (one block per b)
__global__ __launch_bounds__(512) void attn_kernel(const __half* __restrict__ UHh,
                                                   const float* __restrict__ H,
                                                   const float* __restrict__ wq,
                                                   const float* __restrict__ vd,
                                                   float* __restrict__ cbuf,
                                                   float* __restrict__ attn_out,
                                                   float* __restrict__ out,
                                                   int t) {
    __shared__ float wqs[512];
    __shared__ float vs[512];
    __shared__ float es[256];
    __shared__ float red[4];
    __shared__ float red2[4];

    int b = blockIdx.x;
    int tid = threadIdx.x;
    wqs[tid] = wq[(size_t)b * 512 + tid];
    vs[tid]  = vd[tid];
    __syncthreads();

    int wv = tid >> 6, lane = tid & 63;
    // e phase: each wave handles t' = wv, wv+8, ...
    for (int tp = wv; tp < 256; tp += 8) {
        const __half2* uh2 = (const __half2*)(UHh + ((size_t)b * 256 + tp) * 512);
        float acc = 0.0f;
#pragma unroll
        for (int m2 = 0; m2 < 4; m2++) {
            int idx = lane + 64 * m2;
            __half2 h = uh2[idx];
            int n = idx * 2;
            acc = fmaf(fast_tanh(wqs[n]     + __low2float(h)),  vs[n],     acc);
            acc = fmaf(fast_tanh(wqs[n + 1] + __high2float(h)), vs[n + 1], acc);
        }
#pragma unroll
        for (int o = 32; o; o >>= 1) acc += __shfl_xor(acc, o, 64);
        if (lane == 0) es[tp] = acc;
    }
    __syncthreads();

    // softmax over es[0..255] using the first 4 waves
    float v = 0.0f, ex = 0.0f;
    if (tid < 256) {
        v = es[tid];
        float mx = v;
#pragma unroll
        for (int o = 32; o; o >>= 1) mx = fmaxf(mx, __shfl_xor(mx, o, 64));
        if (lane == 0) red[wv] = mx;
    }
    __syncthreads();
    float mall = fmaxf(fmaxf(red[0], red[1]), fmaxf(red[2], red[3]));
    if (tid < 256) {
        ex = __expf(v - mall);
        float s = ex;
#pragma unroll
        for (int o = 32; o; o >>= 1) s += __shfl_xor(s, o, 64);
        if (lane == 0) red2[wv] = s;
    }
    __syncthreads();
    float tot = red2[0] + red2[1] + red2[2] + red2[3];
    float beta = 0.0f;
    if (tid < 256) beta = ex / tot;
    __syncthreads();   // everyone done reading es before overwrite
    if (tid < 256) {
        es[tid] = beta;
        attn_out[(size_t)b * 65536 + (size_t)t * 256 + tid] = beta;
    }
    __syncthreads();

    // c phase: thread tid handles column m = tid (512 threads)
    {
        int m = tid;
        float acc = 0.0f;
        const float* hp = H + (size_t)b * 256 * 512 + m;
#pragma unroll 4
        for (int tp = 0; tp < 256; tp++) acc = fmaf(es[tp], hp[(size_t)tp * 512], acc);
        cbuf[(size_t)b * 512 + m] = acc;
        if (t == 255) out[(size_t)b * 1024 + 512 + m] = acc;
    }
}

// ---------------------------------------------------------------------------
// gates = c @ Wih.T + d @ Whh.T + b_ih + b_hh ; LSTM cell update
// grid (16 b-tiles, 16 p-slices), block 512: thread = (bb in 0..15, pp in 0..31)
__global__ __launch_bounds__(512) void gates_kernel(const float* __restrict__ cbuf,
                                                    const float* __restrict__ dcur,
                                                    const float* __restrict__ scur,
                                                    const float* __restrict__ Wih,
                                                    const float* __restrict__ Whh,
                                                    const float* __restrict__ bih,
                                                    const float* __restrict__ bhh,
                                                    float* __restrict__ dnext,
                                                    float* __restrict__ snext,
                                                    float* __restrict__ out,
                                                    int t) {
    __shared__ float as_[16][1024];  // [c | d] per b
    int tid = threadIdx.x;           // 512
    int b0 = blockIdx.x * 16, p0 = blockIdx.y * 32;
    for (int idx = tid; idx < 16 * 1024; idx += 512) {
        int bb = idx >> 10, j = idx & 1023;
        as_[bb][j] = (j < 512) ? cbuf[(size_t)(b0 + bb) * 512 + j]
                               : dcur[(size_t)(b0 + bb) * 512 + (j - 512)];
    }
    __syncthreads();
    int bb = tid >> 5, pp = tid & 31;
    int b = b0 + bb, p = p0 + pp;

    const float4* c4 = (const float4*)(as_[bb]);
    const float4* d4 = (const float4*)(as_[bb] + 512);
    const float4* wi_i = (const float4*)(Wih + (size_t)(p)          * 512);
    const float4* wi_f = (const float4*)(Wih + (size_t)(512  + p)   * 512);
    const float4* wi_g = (const float4*)(Wih + (size_t)(1024 + p)   * 512);
    const float4* wi_o = (const float4*)(Wih + (size_t)(1536 + p)   * 512);
    const float4* wh_i = (const float4*)(Whh + (size_t)(p)          * 512);
    const float4* wh_f = (const float4*)(Whh + (size_t)(512  + p)   * 512);
    const float4* wh_g = (const float4*)(Whh + (size_t)(1024 + p)   * 512);
    const float4* wh_o = (const float4*)(Whh + (size_t)(1536 + p)   * 512);

    float ai = 0.0f, af = 0.0f, ag = 0.0f, ao = 0.0f;
#pragma unroll 4
    for (int k = 0; k < 128; k++) {
        float4 c = c4[k];
        float4 w;
        w = wi_i[k]; ai = fmaf(c.x,w.x,fmaf(c.y,w.y,fmaf(c.z,w.z,fmaf(c.w,w.w,ai))));
        w = wi_f[k]; af = fmaf(c.x,w.x,fmaf(c.y,w.y,fmaf(c.z,w.z,fmaf(c.w,w.w,af))));
        w = wi_g[k]; ag = fmaf(c.x,w.x,fmaf(c.y,w.y,fmaf(c.z,w.z,fmaf(c.w,w.w,ag))));
        w = wi_o[k]; ao = fmaf(c.x,w.x,fmaf(c.y,w.y,fmaf(c.z,w.z,fmaf(c.w,w.w,ao))));
    }
#pragma unroll 4
    for (int k = 0; k < 128; k++) {
        float4 d = d4[k];
        float4 w;
        w = wh_i[k]; ai = fmaf(d.x,w.x,fmaf(d.y,w.y,fmaf(d.z,w.z,fmaf(d.w,w.w,ai))));
        w = wh_f[k]; af = fmaf(d.x,w.x,fmaf(d.y,w.y,fmaf(d.z,w.z,fmaf(d.w,w.w,af))));
        w = wh_g[k]; ag = fmaf(d.x,w.x,fmaf(d.y,w.y,fmaf(d.z,w.z,fmaf(d.w,w.w,ag))));
        w = wh_o[k]; ao = fmaf(d.x,w.x,fmaf(d.y,w.y,fmaf(d.z,w.z,fmaf(d.w,w.w,ao))));
    }
    ai += bih[p]        + bhh[p];
    af += bih[512 + p]  + bhh[512 + p];
    ag += bih[1024 + p] + bhh[1024 + p];
    ao += bih[1536 + p] + bhh[1536 + p];

    float ig = fast_sigmoid(ai);
    float fg = fast_sigmoid(af);
    float gg = fast_tanh(ag);
    float og = fast_sigmoid(ao);
    float sold = scur[(size_t)b * 512 + p];
    float snew = fmaf(fg, sold, ig * gg);
    float dnew = og * fast_tanh(snew);
    snext[(size_t)b * 512 + p] = snew;
    dnext[(size_t)b * 512 + p] = dnew;
    if (t == 255) out[(size_t)b * 1024 + p] = dnew;
}

// ---------------------------------------------------------------------------
extern "C" void kernel_launch(void* const* d_in, const int* in_sizes, int n_in,
                              void* d_out, int out_size, void* d_ws, size_t ws_size,
                              hipStream_t stream) {
    const float* H   = (const float*)d_in[0];
    const float* d0  = (const float*)d_in[1];
    const float* s0  = (const float*)d_in[2];
    const float* Wd  = (const float*)d_in[3];
    const float* Ud  = (const float*)d_in[4];
    const float* vd  = (const float*)d_in[5];
    const float* Wih = (const float*)d_in[6];
    const float* Whh = (const float*)d_in[7];
    const float* bih = (const float*)d_in[8];
    const float* bhh = (const float*)d_in[9];

    float* out  = (float*)d_out;            // [B,1,1024] = 262144 floats
    float* attn = out + 262144;             // [B,T,T]    = 16777216 floats

    char* ws = (char*)d_ws;
    __half* UHh = (__half*)ws;                                 // 67,108,864 B
    size_t off = (size_t)67108864;
    float* wq   = (float*)(ws + off); off += 524288;
    float* dA   = (float*)(ws + off); off += 524288;
    float* dB   = (float*)(ws + off); off += 524288;
    float* sA   = (float*)(ws + off); off += 524288;
    float* sB   = (float*)(ws + off); off += 524288;
    float* cbuf = (float*)(ws + off); off += 524288;

    init_state<<<512, 256, 0, stream>>>(d0, s0, dA, sA);
    uh_gemm<<<dim3(1024, 8), 256, 0, stream>>>(H, Ud, UHh);

    for (int t = 0; t < 256; t++) {
        const float* dc = (t & 1) ? dB : dA;
        const float* sc = (t & 1) ? sB : sA;
        float* dn = (t & 1) ? dA : dB;
        float* sn = (t & 1) ? sA : sB;
        wq_kernel<<<dim3(16, 16), 512, 0, stream>>>(dc, sc, Wd, wq);
        attn_kernel<<<256, 512, 0, stream>>>(UHh, H, wq, vd, cbuf, attn, out, t);
        gates_kernel<<<dim3(16, 16), 512, 0, stream>>>(cbuf, dc, sc, Wih, Whh, bih, bhh, dn, sn, out, t);
    }
}

// Round 2
// 48205.902 us; speedup vs baseline: 1.8610x; 1.8610x over previous
//
#include <hip/hip_runtime.h>
#include <hip/hip_fp16.h>

// Problem constants: B=256, T=256, M=512, P=512
typedef _Float16 h2 __attribute__((ext_vector_type(2)));
typedef _Float16 h4 __attribute__((ext_vector_type(4)));
typedef _Float16 h8 __attribute__((ext_vector_type(8)));

#define H2OF(v, i) __builtin_shufflevector((v), (v), 2*(i), 2*(i)+1)

__device__ __forceinline__ float fdot2(h2 a, h2 b, float c) {
    return __builtin_amdgcn_fdot2(a, b, c, false);
}
__device__ __forceinline__ float fast_tanh(float x) {
    float e = __expf(2.0f * x);                         // v_mul + v_exp
    return 1.0f - 2.0f * __builtin_amdgcn_rcpf(e + 1.0f);
}
__device__ __forceinline__ float fast_sigmoid(float x) {
    return __builtin_amdgcn_rcpf(1.0f + __expf(-x));
}

// ---------------------------------------------------------------------------
// f32 -> f16 convert, 4 elements/thread (all sizes divisible by 4)
__global__ void convert_f16(const float* __restrict__ s, _Float16* __restrict__ d, int n) {
    int i = (blockIdx.x * 256 + threadIdx.x) * 4;
    if (i < n) {
        float4 v = *(const float4*)(s + i);
        h4 o = {(_Float16)v.x, (_Float16)v.y, (_Float16)v.z, (_Float16)v.w};
        *(h4*)(d + i) = o;
    }
}

// ---------------------------------------------------------------------------
__global__ void init_state(const float* __restrict__ d0, const float* __restrict__ s0,
                           float* __restrict__ sA,
                           _Float16* __restrict__ dh, _Float16* __restrict__ sh) {
    int i = blockIdx.x * 256 + threadIdx.x;   // 512 x 256 = 131072
    float dv = d0[i], sv = s0[i];
    sA[i] = sv;
    dh[i] = (_Float16)dv;
    sh[i] = (_Float16)sv;
}

// ---------------------------------------------------------------------------
// UHh[r, n] = (f16) sum_k H[r,k] * Ud[n,k];  r in [0,65536), n,k in [0,512)
__global__ __launch_bounds__(256) void uh_gemm(const float* __restrict__ H,
                                               const float* __restrict__ Ud,
                                               _Float16* __restrict__ UHh) {
    __shared__ float As[16][65];
    __shared__ float Bs[16][65];
    int tid = threadIdx.x;
    int tx = tid & 15;
    int ty = tid >> 4;
    int r0 = blockIdx.x * 64;
    int n0 = blockIdx.y * 64;
    int lr = tid >> 2;
    int lk = (tid & 3) * 4;

    float acc[4][4];
#pragma unroll
    for (int i = 0; i < 4; i++)
#pragma unroll
        for (int j = 0; j < 4; j++) acc[i][j] = 0.0f;

    for (int k0 = 0; k0 < 512; k0 += 16) {
        float4 a4 = *(const float4*)(H  + (size_t)(r0 + lr) * 512 + k0 + lk);
        float4 b4 = *(const float4*)(Ud + (size_t)(n0 + lr) * 512 + k0 + lk);
        As[lk + 0][lr] = a4.x; As[lk + 1][lr] = a4.y;
        As[lk + 2][lr] = a4.z; As[lk + 3][lr] = a4.w;
        Bs[lk + 0][lr] = b4.x; Bs[lk + 1][lr] = b4.y;
        Bs[lk + 2][lr] = b4.z; Bs[lk + 3][lr] = b4.w;
        __syncthreads();
#pragma unroll
        for (int kk = 0; kk < 16; kk++) {
            float a[4], b[4];
#pragma unroll
            for (int i = 0; i < 4; i++) a[i] = As[kk][ty + 16 * i];
#pragma unroll
            for (int j = 0; j < 4; j++) b[j] = Bs[kk][tx + 16 * j];
#pragma unroll
            for (int i = 0; i < 4; i++)
#pragma unroll
                for (int j = 0; j < 4; j++) acc[i][j] = fmaf(a[i], b[j], acc[i][j]);
        }
        __syncthreads();
    }
#pragma unroll
    for (int i = 0; i < 4; i++)
#pragma unroll
        for (int j = 0; j < 4; j++)
            UHh[(size_t)(r0 + ty + 16 * i) * 512 + (n0 + tx + 16 * j)] = (_Float16)acc[i][j];
}

// ---------------------------------------------------------------------------
// wq[b,n] = sum_j q[b,j] * Wd[n,j],  q = [d|s] f16.  grid (8 b-tiles, 32 n-tiles), 512 thr
__global__ __launch_bounds__(512) void wq_kernel(const _Float16* __restrict__ dh,
                                                 const _Float16* __restrict__ sh,
                                                 const _Float16* __restrict__ Wdh,
                                                 float* __restrict__ wq) {
    __shared__ _Float16 qs[32 * 1024];   // 64 KB
    int tid = threadIdx.x;
    int b0 = blockIdx.x * 32;
#pragma unroll
    for (int k = 0; k < 8; k++) {
        int pos = (tid + k * 512) * 8;
        int bb = pos >> 10, c = pos & 1023;
        const _Float16* src = (c < 512) ? dh + (size_t)(b0 + bb) * 512 + c
                                        : sh + (size_t)(b0 + bb) * 512 + (c - 512);
        *(h8*)(qs + pos) = *(const h8*)src;
    }
    __syncthreads();
    int bb = tid >> 4, nn = tid & 15;
    int n = blockIdx.y * 16 + nn;
    const h8* w8 = (const h8*)(Wdh + (size_t)n * 1024);
    const h8* q8 = (const h8*)(qs + bb * 1024);
    float a0 = 0.0f, a1 = 0.0f;
#pragma unroll 4
    for (int k = 0; k < 128; k++) {
        h8 wv = w8[k], qv = q8[k];
        a0 = fdot2(H2OF(qv, 0), H2OF(wv, 0), a0);
        a1 = fdot2(H2OF(qv, 1), H2OF(wv, 1), a1);
        a0 = fdot2(H2OF(qv, 2), H2OF(wv, 2), a0);
        a1 = fdot2(H2OF(qv, 3), H2OF(wv, 3), a1);
    }
    wq[(size_t)(b0 + bb) * 512 + n] = a0 + a1;
}

// ---------------------------------------------------------------------------
// Per-b attention. grid 256 (block per b), 512 threads.
__global__ __launch_bounds__(512) void attn_kernel(const _Float16* __restrict__ UHh,
                                                   const _Float16* __restrict__ Hh,
                                                   const float* __restrict__ Hf,
                                                   const float* __restrict__ wq,
                                                   const float* __restrict__ vd,
                                                   _Float16* __restrict__ ch,
                                                   float* __restrict__ attn_out,
                                                   float* __restrict__ out,
                                                   int t) {
    __shared__ float wqs[512];
    __shared__ float vs[512];
    __shared__ float es[256];
    __shared__ float red[4];
    __shared__ float red2[4];
    __shared__ float part[4][512];

    int b = blockIdx.x;
    int tid = threadIdx.x;
    wqs[tid] = wq[(size_t)b * 512 + tid];
    vs[tid]  = vd[tid];
    __syncthreads();

    int wv = tid >> 6, lane = tid & 63;
    // e phase: wave per t'
    for (int tp = wv; tp < 256; tp += 8) {
        const h2* uh2 = (const h2*)(UHh + ((size_t)b * 256 + tp) * 512);
        float acc = 0.0f;
#pragma unroll
        for (int m2 = 0; m2 < 4; m2++) {
            int idx = lane + 64 * m2;
            h2 u = uh2[idx];
            int n = idx * 2;
            acc = fmaf(fast_tanh(wqs[n]     + (float)u[0]), vs[n],     acc);
            acc = fmaf(fast_tanh(wqs[n + 1] + (float)u[1]), vs[n + 1], acc);
        }
#pragma unroll
        for (int o = 32; o; o >>= 1) acc += __shfl_xor(acc, o, 64);
        if (lane == 0) es[tp] = acc;
    }
    __syncthreads();

    // softmax over es[0..255]
    float v = 0.0f, ex = 0.0f;
    if (tid < 256) {
        v = es[tid];
        float mx = v;
#pragma unroll
        for (int o = 32; o; o >>= 1) mx = fmaxf(mx, __shfl_xor(mx, o, 64));
        if (lane == 0) red[wv] = mx;
    }
    __syncthreads();
    float mall = fmaxf(fmaxf(red[0], red[1]), fmaxf(red[2], red[3]));
    if (tid < 256) {
        ex = __expf(v - mall);
        float s = ex;
#pragma unroll
        for (int o = 32; o; o >>= 1) s += __shfl_xor(s, o, 64);
        if (lane == 0) red2[wv] = s;
    }
    __syncthreads();
    float tot = red2[0] + red2[1] + red2[2] + red2[3];
    float beta = 0.0f;
    if (tid < 256) beta = ex / tot;
    __syncthreads();
    if (tid < 256) {
        es[tid] = beta;
        attn_out[(size_t)b * 65536 + (size_t)t * 256 + tid] = beta;
    }
    __syncthreads();

    // c phase: thread (g = m-group of 4, qq = tp quarter)
    int g = tid & 127, qq = tid >> 7;
    float a0 = 0, a1 = 0, a2 = 0, a3 = 0;
    if (Hh) {
        const h4* hp = (const h4*)(Hh + ((size_t)b * 256 + qq * 64) * 512 + g * 4);
#pragma unroll 8
        for (int i = 0; i < 64; i++) {
            h4 hv = hp[(size_t)i * 128];
            float bt = es[qq * 64 + i];
            a0 = fmaf(bt, (float)hv[0], a0);
            a1 = fmaf(bt, (float)hv[1], a1);
            a2 = fmaf(bt, (float)hv[2], a2);
            a3 = fmaf(bt, (float)hv[3], a3);
        }
    } else {
        const float4* hp = (const float4*)(Hf + ((size_t)b * 256 + qq * 64) * 512 + g * 4);
#pragma unroll 4
        for (int i = 0; i < 64; i++) {
            float4 hv = hp[(size_t)i * 128];
            float bt = es[qq * 64 + i];
            a0 = fmaf(bt, hv.x, a0);
            a1 = fmaf(bt, hv.y, a1);
            a2 = fmaf(bt, hv.z, a2);
            a3 = fmaf(bt, hv.w, a3);
        }
    }
    *(float4*)&part[qq][g * 4] = make_float4(a0, a1, a2, a3);
    __syncthreads();
    {
        int m = tid;
        float c = part[0][m] + part[1][m] + part[2][m] + part[3][m];
        ch[(size_t)b * 512 + m] = (_Float16)c;
        if (t == 255) out[(size_t)b * 1024 + 512 + m] = c;
    }
}

// ---------------------------------------------------------------------------
// gates + LSTM cell. grid (8 b-tiles, 32 p-tiles of 16), 512 threads.
__global__ __launch_bounds__(512) void gates_kernel(const _Float16* __restrict__ ch,
                                                    const _Float16* __restrict__ dh,
                                                    const float* __restrict__ scur,
                                                    const _Float16* __restrict__ Wihh,
                                                    const _Float16* __restrict__ Whhh,
                                                    const float* __restrict__ bih,
                                                    const float* __restrict__ bhh,
                                                    float* __restrict__ snext,
                                                    _Float16* __restrict__ dhn,
                                                    _Float16* __restrict__ shn,
                                                    float* __restrict__ out,
                                                    int t) {
    __shared__ _Float16 qg[32 * 1024];   // [c(512) | d(512)] per b, 64 KB
    int tid = threadIdx.x;
    int b0 = blockIdx.x * 32;
#pragma unroll
    for (int k = 0; k < 8; k++) {
        int pos = (tid + k * 512) * 8;
        int bb = pos >> 10, c = pos & 1023;
        const _Float16* src = (c < 512) ? ch + (size_t)(b0 + bb) * 512 + c
                                        : dh + (size_t)(b0 + bb) * 512 + (c - 512);
        *(h8*)(qg + pos) = *(const h8*)src;
    }
    __syncthreads();
    int bb = tid >> 4, pp = tid & 15;
    int p = blockIdx.y * 16 + pp;
    int b = b0 + bb;

    const h8* qc = (const h8*)(qg + bb * 1024);       // 64 chunks c, then 64 chunks d
    const h8* qd = qc + 64;
    const h8* wi0 = (const h8*)(Wihh + (size_t)(p)         * 512);
    const h8* wi1 = (const h8*)(Wihh + (size_t)(512 + p)   * 512);
    const h8* wi2 = (const h8*)(Wihh + (size_t)(1024 + p)  * 512);
    const h8* wi3 = (const h8*)(Wihh + (size_t)(1536 + p)  * 512);
    const h8* wh0 = (const h8*)(Whhh + (size_t)(p)         * 512);
    const h8* wh1 = (const h8*)(Whhh + (size_t)(512 + p)   * 512);
    const h8* wh2 = (const h8*)(Whhh + (size_t)(1024 + p)  * 512);
    const h8* wh3 = (const h8*)(Whhh + (size_t)(1536 + p)  * 512);

    float ai = 0, af = 0, ag = 0, ao = 0;
#pragma unroll 2
    for (int k = 0; k < 64; k++) {
        h8 q = qc[k];
        h2 q0 = H2OF(q, 0), q1 = H2OF(q, 1), q2 = H2OF(q, 2), q3 = H2OF(q, 3);
        h8 w;
        w = wi0[k]; ai = fdot2(q0, H2OF(w,0), ai); ai = fdot2(q1, H2OF(w,1), ai);
                    ai = fdot2(q2, H2OF(w,2), ai); ai = fdot2(q3, H2OF(w,3), ai);
        w = wi1[k]; af = fdot2(q0, H2OF(w,0), af); af = fdot2(q1, H2OF(w,1), af);
                    af = fdot2(q2, H2OF(w,2), af); af = fdot2(q3, H2OF(w,3), af);
        w = wi2[k]; ag = fdot2(q0, H2OF(w,0), ag); ag = fdot2(q1, H2OF(w,1), ag);
                    ag = fdot2(q2, H2OF(w,2), ag); ag = fdot2(q3, H2OF(w,3), ag);
        w = wi3[k]; ao = fdot2(q0, H2OF(w,0), ao); ao = fdot2(q1, H2OF(w,1), ao);
                    ao = fdot2(q2, H2OF(w,2), ao); ao = fdot2(q3, H2OF(w,3), ao);
    }
#pragma unroll 2
    for (int k = 0; k < 64; k++) {
        h8 q = qd[k];
        h2 q0 = H2OF(q, 0), q1 = H2OF(q, 1), q2 = H2OF(q, 2), q3 = H2OF(q, 3);
        h8 w;
        w = wh0[k]; ai = fdot2(q0, H2OF(w,0), ai); ai = fdot2(q1, H2OF(w,1), ai);
                    ai = fdot2(q2, H2OF(w,2), ai); ai = fdot2(q3, H2OF(w,3), ai);
        w = wh1[k]; af = fdot2(q0, H2OF(w,0), af); af = fdot2(q1, H2OF(w,1), af);
                    af = fdot2(q2, H2OF(w,2), af); af = fdot2(q3, H2OF(w,3), af);
        w = wh2[k]; ag = fdot2(q0, H2OF(w,0), ag); ag = fdot2(q1, H2OF(w,1), ag);
                    ag = fdot2(q2, H2OF(w,2), ag); ag = fdot2(q3, H2OF(w,3), ag);
        w = wh3[k]; ao = fdot2(q0, H2OF(w,0), ao); ao = fdot2(q1, H2OF(w,1), ao);
                    ao = fdot2(q2, H2OF(w,2), ao); ao = fdot2(q3, H2OF(w,3), ao);
    }

    ai += bih[p]        + bhh[p];
    af += bih[512 + p]  + bhh[512 + p];
    ag += bih[1024 + p] + bhh[1024 + p];
    ao += bih[1536 + p] + bhh[1536 + p];

    float ig = fast_sigmoid(ai);
    float fg = fast_sigmoid(af);
    float gg = fast_tanh(ag);
    float og = fast_sigmoid(ao);
    float sold = scur[(size_t)b * 512 + p];
    float snew = fmaf(fg, sold, ig * gg);
    float dnew = og * fast_tanh(snew);
    snext[(size_t)b * 512 + p] = snew;
    dhn[(size_t)b * 512 + p] = (_Float16)dnew;
    shn[(size_t)b * 512 + p] = (_Float16)snew;
    if (t == 255) out[(size_t)b * 1024 + p] = dnew;
}

// ---------------------------------------------------------------------------
extern "C" void kernel_launch(void* const* d_in, const int* in_sizes, int n_in,
                              void* d_out, int out_size, void* d_ws, size_t ws_size,
                              hipStream_t stream) {
    const float* H   = (const float*)d_in[0];
    const float* d0  = (const float*)d_in[1];
    const float* s0  = (const float*)d_in[2];
    const float* Wd  = (const float*)d_in[3];
    const float* Ud  = (const float*)d_in[4];
    const float* vd  = (const float*)d_in[5];
    const float* Wih = (const float*)d_in[6];
    const float* Whh = (const float*)d_in[7];
    const float* bih = (const float*)d_in[8];
    const float* bhh = (const float*)d_in[9];

    float* out  = (float*)d_out;            // [B,1,1024]
    float* attn = out + 262144;             // [B,T,T]

    char* ws = (char*)d_ws;
    size_t off = 0;
    _Float16* UHh  = (_Float16*)(ws + off); off += 67108864;
    _Float16* Wdh  = (_Float16*)(ws + off); off += 1048576;
    _Float16* Wihh = (_Float16*)(ws + off); off += 2097152;
    _Float16* Whhh = (_Float16*)(ws + off); off += 2097152;
    float*    wq   = (float*)   (ws + off); off += 524288;
    float*    sA   = (float*)   (ws + off); off += 524288;
    float*    sB   = (float*)   (ws + off); off += 524288;
    _Float16* dhA  = (_Float16*)(ws + off); off += 262144;
    _Float16* dhB  = (_Float16*)(ws + off); off += 262144;
    _Float16* shA  = (_Float16*)(ws + off); off += 262144;
    _Float16* shB  = (_Float16*)(ws + off); off += 262144;
    _Float16* ch   = (_Float16*)(ws + off); off += 262144;
    _Float16* Hh   = nullptr;
    if (ws_size >= off + 67108864) { Hh = (_Float16*)(ws + off); off += 67108864; }

    convert_f16<<<512,  256, 0, stream>>>(Wd,  Wdh,  524288);
    convert_f16<<<1024, 256, 0, stream>>>(Wih, Wihh, 1048576);
    convert_f16<<<1024, 256, 0, stream>>>(Whh, Whhh, 1048576);
    if (Hh) convert_f16<<<32768, 256, 0, stream>>>(H, Hh, 33554432);
    init_state<<<512, 256, 0, stream>>>(d0, s0, sA, dhA, shA);
    uh_gemm<<<dim3(1024, 8), 256, 0, stream>>>(H, Ud, UHh);

    for (int t = 0; t < 256; t++) {
        const _Float16* dhc = (t & 1) ? dhB : dhA;
        const _Float16* shc = (t & 1) ? shB : shA;
        const float*    sc  = (t & 1) ? sB  : sA;
        _Float16* dhn = (t & 1) ? dhA : dhB;
        _Float16* shn = (t & 1) ? shA : shB;
        float*    sn  = (t & 1) ? sA  : sB;
        wq_kernel<<<dim3(8, 32), 512, 0, stream>>>(dhc, shc, Wdh, wq);
        attn_kernel<<<256, 512, 0, stream>>>(UHh, Hh, H, wq, vd, ch, attn, out, t);
        gates_kernel<<<dim3(8, 32), 512, 0, stream>>>(ch, dhc, sc, Wihh, Whhh, bih, bhh, sn, dhn, shn, out, t);
    }
}

// Round 3
// 47901.318 us; speedup vs baseline: 1.8728x; 1.0064x over previous
//
#include <hip/hip_runtime.h>
#include <hip/hip_fp16.h>

// Problem constants: B=256, T=256, M=512, P=512
typedef _Float16 h2 __attribute__((ext_vector_type(2)));
typedef _Float16 h4 __attribute__((ext_vector_type(4)));
typedef _Float16 h8 __attribute__((ext_vector_type(8)));

#define H2OF(v, i) __builtin_shufflevector((v), (v), 2*(i), 2*(i)+1)
#define SC2LOG2E 2.8853900817779268f   // 2 * log2(e)

__device__ __forceinline__ float fdot2(h2 a, h2 b, float c) {
    return __builtin_amdgcn_fdot2(a, b, c, false);
}
// native exp2 / rcp via ISA (v_exp_f32 IS exp2)
__device__ __forceinline__ float v_exp2(float x) { float r; asm("v_exp_f32 %0, %1" : "=v"(r) : "v"(x)); return r; }
__device__ __forceinline__ float v_rcp (float x) { float r; asm("v_rcp_f32 %0, %1" : "=v"(r) : "v"(x)); return r; }
__device__ __forceinline__ float fast_tanh(float x) {
    float e = __expf(2.0f * x);
    return 1.0f - 2.0f * v_rcp(e + 1.0f);
}
__device__ __forceinline__ float fast_sigmoid(float x) {
    return v_rcp(1.0f + __expf(-x));
}

// ---------------------------------------------------------------------------
__global__ void convert_f16(const float* __restrict__ s, _Float16* __restrict__ d, int n) {
    int i = (blockIdx.x * 256 + threadIdx.x) * 4;
    if (i < n) {
        float4 v = *(const float4*)(s + i);
        h4 o = {(_Float16)v.x, (_Float16)v.y, (_Float16)v.z, (_Float16)v.w};
        *(h4*)(d + i) = o;
    }
}

// ---------------------------------------------------------------------------
__global__ void init_state(const float* __restrict__ d0, const float* __restrict__ s0,
                           float* __restrict__ sA,
                           _Float16* __restrict__ dh, _Float16* __restrict__ sh) {
    int i = blockIdx.x * 256 + threadIdx.x;   // 512 x 256 = 131072
    float dv = d0[i], sv = s0[i];
    sA[i] = sv;
    dh[i] = (_Float16)dv;
    sh[i] = (_Float16)sv;
}

// ---------------------------------------------------------------------------
// UH2[r, n] = (f16) (2*log2e) * sum_k H[r,k] * Ud[n,k]
__global__ __launch_bounds__(256) void uh_gemm(const float* __restrict__ H,
                                               const float* __restrict__ Ud,
                                               _Float16* __restrict__ UH2) {
    __shared__ float As[16][65];
    __shared__ float Bs[16][65];
    int tid = threadIdx.x;
    int tx = tid & 15;
    int ty = tid >> 4;
    int r0 = blockIdx.x * 64;
    int n0 = blockIdx.y * 64;
    int lr = tid >> 2;
    int lk = (tid & 3) * 4;

    float acc[4][4];
#pragma unroll
    for (int i = 0; i < 4; i++)
#pragma unroll
        for (int j = 0; j < 4; j++) acc[i][j] = 0.0f;

    for (int k0 = 0; k0 < 512; k0 += 16) {
        float4 a4 = *(const float4*)(H  + (size_t)(r0 + lr) * 512 + k0 + lk);
        float4 b4 = *(const float4*)(Ud + (size_t)(n0 + lr) * 512 + k0 + lk);
        As[lk + 0][lr] = a4.x; As[lk + 1][lr] = a4.y;
        As[lk + 2][lr] = a4.z; As[lk + 3][lr] = a4.w;
        Bs[lk + 0][lr] = b4.x; Bs[lk + 1][lr] = b4.y;
        Bs[lk + 2][lr] = b4.z; Bs[lk + 3][lr] = b4.w;
        __syncthreads();
#pragma unroll
        for (int kk = 0; kk < 16; kk++) {
            float a[4], b[4];
#pragma unroll
            for (int i = 0; i < 4; i++) a[i] = As[kk][ty + 16 * i];
#pragma unroll
            for (int j = 0; j < 4; j++) b[j] = Bs[kk][tx + 16 * j];
#pragma unroll
            for (int i = 0; i < 4; i++)
#pragma unroll
                for (int j = 0; j < 4; j++) acc[i][j] = fmaf(a[i], b[j], acc[i][j]);
        }
        __syncthreads();
    }
#pragma unroll
    for (int i = 0; i < 4; i++)
#pragma unroll
        for (int j = 0; j < 4; j++)
            UH2[(size_t)(r0 + ty + 16 * i) * 512 + (n0 + tx + 16 * j)] =
                (_Float16)(acc[i][j] * SC2LOG2E);
}

// ---------------------------------------------------------------------------
// wq2[b,n] = 2log2e * sum_j q[b,j] * Wd[n,j], q=[d|s].
// grid (32 n-tiles of 16, 8 b-tiles of 32), 1024 threads, k-split by tid>>9.
__global__ __launch_bounds__(1024) void wq_kernel(const _Float16* __restrict__ dh,
                                                  const _Float16* __restrict__ sh,
                                                  const _Float16* __restrict__ Wdh,
                                                  float* __restrict__ wq2) {
    __shared__ _Float16 qs[32 * 1024];   // 64 KB  [b][d(512)|s(512)]
    __shared__ float part[2][512];
    int tid = threadIdx.x;
    int n0 = blockIdx.x * 16, b0 = blockIdx.y * 32;
#pragma unroll
    for (int k = 0; k < 4; k++) {
        int cidx = tid + k * 1024;          // h8-chunk id, 4096 total
        int bb = cidx >> 7, cc = cidx & 127;
        const _Float16* src = (cc < 64) ? dh + (size_t)(b0 + bb) * 512 + cc * 8
                                        : sh + (size_t)(b0 + bb) * 512 + (cc - 64) * 8;
        *(h8*)(qs + bb * 1024 + cc * 8) = *(const h8*)src;
    }
    __syncthreads();
    int kh = tid >> 9, r = tid & 511;
    int bb = r >> 4, nn = r & 15;
    int n = n0 + nn;
    const h8* w8 = (const h8*)(Wdh + (size_t)n * 1024) + kh * 64;
    const h8* q8 = (const h8*)(qs + bb * 1024) + kh * 64;
    float a0 = 0.0f, a1 = 0.0f;
#pragma unroll 2
    for (int k = 0; k < 64; k++) {
        h8 q = q8[k], w = w8[k];
        a0 = fdot2(H2OF(q, 0), H2OF(w, 0), a0);
        a1 = fdot2(H2OF(q, 1), H2OF(w, 1), a1);
        a0 = fdot2(H2OF(q, 2), H2OF(w, 2), a0);
        a1 = fdot2(H2OF(q, 3), H2OF(w, 3), a1);
    }
    part[kh][r] = a0 + a1;
    __syncthreads();
    if (tid < 512) {
        int bb2 = tid >> 4, nn2 = tid & 15;
        wq2[(size_t)(b0 + bb2) * 512 + n0 + nn2] = (part[0][tid] + part[1][tid]) * SC2LOG2E;
    }
}

// ---------------------------------------------------------------------------
// Per-b attention. grid 256 (block per b), 1024 threads (16 waves).
// e = const - 2*sum_n v[n]*r,  r = 1/(1+exp2(wq2+UH2));  softmax; c = beta @ H
__global__ __launch_bounds__(1024) void attn_kernel(const _Float16* __restrict__ UH2,
                                                    const _Float16* __restrict__ Hh,
                                                    const float* __restrict__ Hf,
                                                    const float* __restrict__ wq2,
                                                    const float* __restrict__ vd,
                                                    _Float16* __restrict__ ch,
                                                    float* __restrict__ attn_out,
                                                    float* __restrict__ out,
                                                    int t) {
    __shared__ float es[256];
    __shared__ float red[4];
    __shared__ float red2[4];
    __shared__ float part[8][512];

    int b = blockIdx.x;
    int tid = threadIdx.x;
    int wv = tid >> 6, lane = tid & 63;

    // per-lane fixed columns: cols lane*8 .. lane*8+7
    const float4* wqp = (const float4*)(wq2 + (size_t)b * 512 + lane * 8);
    float4 w0 = wqp[0], w1 = wqp[1];
    const float4* vp = (const float4*)(vd + lane * 8);
    float4 vv0 = vp[0], vv1 = vp[1];
    float wr[8] = {w0.x, w0.y, w0.z, w0.w, w1.x, w1.y, w1.z, w1.w};
    float vr[8] = {vv0.x, vv0.y, vv0.z, vv0.w, vv1.x, vv1.y, vv1.z, vv1.w};

    // e phase: wave wv handles rows [wv*16, wv*16+16)
    const h8* up = (const h8*)(UH2 + (size_t)b * 256 * 512) + lane;
#pragma unroll 2
    for (int i = 0; i < 16; i++) {
        int tp = wv * 16 + i;
        h8 u = up[(size_t)tp * 64];
        float acc = 0.0f;
#pragma unroll
        for (int j = 0; j < 8; j++) {
            float z = wr[j] + (float)u[j];
            float r = v_rcp(1.0f + v_exp2(z));
            acc = fmaf(vr[j], r, acc);
        }
#pragma unroll
        for (int o = 32; o; o >>= 1) acc += __shfl_xor(acc, o, 64);
        if (lane == 0) es[tp] = -2.0f * acc;
    }
    __syncthreads();

    // softmax over es[0..255] (first 4 waves)
    float v = 0.0f, ex = 0.0f;
    if (tid < 256) {
        v = es[tid];
        float mx = v;
#pragma unroll
        for (int o = 32; o; o >>= 1) mx = fmaxf(mx, __shfl_xor(mx, o, 64));
        if (lane == 0) red[wv] = mx;
    }
    __syncthreads();
    float mall = fmaxf(fmaxf(red[0], red[1]), fmaxf(red[2], red[3]));
    if (tid < 256) {
        ex = __expf(v - mall);
        float s = ex;
#pragma unroll
        for (int o = 32; o; o >>= 1) s += __shfl_xor(s, o, 64);
        if (lane == 0) red2[wv] = s;
    }
    __syncthreads();
    float tot = red2[0] + red2[1] + red2[2] + red2[3];
    float beta = 0.0f;
    if (tid < 256) beta = ex * v_rcp(tot);
    __syncthreads();
    if (tid < 256) {
        es[tid] = beta;
        attn_out[(size_t)b * 65536 + (size_t)t * 256 + tid] = beta;
    }
    __syncthreads();

    // c phase: tc = t'-chunk (8 x 32), g = m-group of 4 (128 groups)
    int tc = tid >> 7, g = tid & 127;
    float a0 = 0, a1 = 0, a2 = 0, a3 = 0;
    if (Hh) {
        const h4* hp = (const h4*)(Hh + ((size_t)b * 256 + tc * 32) * 512) + g;
#pragma unroll 4
        for (int i = 0; i < 32; i++) {
            h4 hv = hp[(size_t)i * 128];
            float bt = es[tc * 32 + i];
            a0 = fmaf(bt, (float)hv[0], a0);
            a1 = fmaf(bt, (float)hv[1], a1);
            a2 = fmaf(bt, (float)hv[2], a2);
            a3 = fmaf(bt, (float)hv[3], a3);
        }
    } else {
        const float4* hp = (const float4*)(Hf + ((size_t)b * 256 + tc * 32) * 512) + g;
#pragma unroll 4
        for (int i = 0; i < 32; i++) {
            float4 hv = hp[(size_t)i * 128];
            float bt = es[tc * 32 + i];
            a0 = fmaf(bt, hv.x, a0);
            a1 = fmaf(bt, hv.y, a1);
            a2 = fmaf(bt, hv.z, a2);
            a3 = fmaf(bt, hv.w, a3);
        }
    }
    *(float4*)&part[tc][g * 4] = make_float4(a0, a1, a2, a3);
    __syncthreads();
    if (tid < 512) {
        int m = tid;
        float c = part[0][m] + part[1][m] + part[2][m] + part[3][m]
                + part[4][m] + part[5][m] + part[6][m] + part[7][m];
        ch[(size_t)b * 512 + m] = (_Float16)c;
        if (t == 255) out[(size_t)b * 1024 + 512 + m] = c;
    }
}

// ---------------------------------------------------------------------------
// gates + LSTM cell. grid (32 p-tiles of 16, 8 b-tiles of 32), 1024 threads.
// k-split: kh=0 -> c@Wih part, kh=1 -> d@Whh part; combine via LDS.
__global__ __launch_bounds__(1024) void gates_kernel(const _Float16* __restrict__ ch,
                                                     const _Float16* __restrict__ dh,
                                                     const float* __restrict__ scur,
                                                     const _Float16* __restrict__ Wihh,
                                                     const _Float16* __restrict__ Whhh,
                                                     const float* __restrict__ bih,
                                                     const float* __restrict__ bhh,
                                                     float* __restrict__ snext,
                                                     _Float16* __restrict__ dhn,
                                                     _Float16* __restrict__ shn,
                                                     float* __restrict__ out,
                                                     int t) {
    __shared__ _Float16 qg[32 * 1024];   // 64 KB  [b][c(512)|d(512)]
    __shared__ float pI[2][512];
    __shared__ float pF[2][512];
    __shared__ float pG[2][512];
    __shared__ float pO[2][512];
    int tid = threadIdx.x;
    int p0 = blockIdx.x * 16, b0 = blockIdx.y * 32;
#pragma unroll
    for (int k = 0; k < 4; k++) {
        int cidx = tid + k * 1024;
        int bb = cidx >> 7, cc = cidx & 127;
        const _Float16* src = (cc < 64) ? ch + (size_t)(b0 + bb) * 512 + cc * 8
                                        : dh + (size_t)(b0 + bb) * 512 + (cc - 64) * 8;
        *(h8*)(qg + bb * 1024 + cc * 8) = *(const h8*)src;
    }
    __syncthreads();
    int kh = tid >> 9, r = tid & 511;
    int bb = r >> 4, pp = r & 15;
    int p = p0 + pp;
    const _Float16* W = kh ? Whhh : Wihh;
    const h8* w0 = (const h8*)(W + (size_t)(p)        * 512);
    const h8* w1 = (const h8*)(W + (size_t)(512 + p)  * 512);
    const h8* w2 = (const h8*)(W + (size_t)(1024 + p) * 512);
    const h8* w3 = (const h8*)(W + (size_t)(1536 + p) * 512);
    const h8* q8 = (const h8*)(qg + bb * 1024 + kh * 512);

    float ai = 0, af = 0, ag = 0, ao = 0;
#pragma unroll 2
    for (int k = 0; k < 64; k++) {
        h8 q = q8[k];
        h2 q0 = H2OF(q, 0), q1 = H2OF(q, 1), q2 = H2OF(q, 2), q3 = H2OF(q, 3);
        h8 w;
        w = w0[k]; ai = fdot2(q0, H2OF(w,0), ai); ai = fdot2(q1, H2OF(w,1), ai);
                   ai = fdot2(q2, H2OF(w,2), ai); ai = fdot2(q3, H2OF(w,3), ai);
        w = w1[k]; af = fdot2(q0, H2OF(w,0), af); af = fdot2(q1, H2OF(w,1), af);
                   af = fdot2(q2, H2OF(w,2), af); af = fdot2(q3, H2OF(w,3), af);
        w = w2[k]; ag = fdot2(q0, H2OF(w,0), ag); ag = fdot2(q1, H2OF(w,1), ag);
                   ag = fdot2(q2, H2OF(w,2), ag); ag = fdot2(q3, H2OF(w,3), ag);
        w = w3[k]; ao = fdot2(q0, H2OF(w,0), ao); ao = fdot2(q1, H2OF(w,1), ao);
                   ao = fdot2(q2, H2OF(w,2), ao); ao = fdot2(q3, H2OF(w,3), ao);
    }
    pI[kh][r] = ai; pF[kh][r] = af; pG[kh][r] = ag; pO[kh][r] = ao;
    __syncthreads();

    if (tid < 512) {
        int rr = tid;
        int bb2 = rr >> 4, pp2 = rr & 15;
        int p2 = p0 + pp2, b2 = b0 + bb2;
        float gi = pI[0][rr] + pI[1][rr] + bih[p2]        + bhh[p2];
        float gf = pF[0][rr] + pF[1][rr] + bih[512 + p2]  + bhh[512 + p2];
        float gg = pG[0][rr] + pG[1][rr] + bih[1024 + p2] + bhh[1024 + p2];
        float go = pO[0][rr] + pO[1][rr] + bih[1536 + p2] + bhh[1536 + p2];

        float ig = fast_sigmoid(gi);
        float fg = fast_sigmoid(gf);
        float g_ = fast_tanh(gg);
        float og = fast_sigmoid(go);
        float sold = scur[(size_t)b2 * 512 + p2];
        float snew = fmaf(fg, sold, ig * g_);
        float dnew = og * fast_tanh(snew);
        snext[(size_t)b2 * 512 + p2] = snew;
        dhn[(size_t)b2 * 512 + p2] = (_Float16)dnew;
        shn[(size_t)b2 * 512 + p2] = (_Float16)snew;
        if (t == 255) out[(size_t)b2 * 1024 + p2] = dnew;
    }
}

// ---------------------------------------------------------------------------
extern "C" void kernel_launch(void* const* d_in, const int* in_sizes, int n_in,
                              void* d_out, int out_size, void* d_ws, size_t ws_size,
                              hipStream_t stream) {
    const float* H   = (const float*)d_in[0];
    const float* d0  = (const float*)d_in[1];
    const float* s0  = (const float*)d_in[2];
    const float* Wd  = (const float*)d_in[3];
    const float* Ud  = (const float*)d_in[4];
    const float* vd  = (const float*)d_in[5];
    const float* Wih = (const float*)d_in[6];
    const float* Whh = (const float*)d_in[7];
    const float* bih = (const float*)d_in[8];
    const float* bhh = (const float*)d_in[9];

    float* out  = (float*)d_out;            // [B,1,1024]
    float* attn = out + 262144;             // [B,T,T]

    char* ws = (char*)d_ws;
    size_t off = 0;
    _Float16* UH2  = (_Float16*)(ws + off); off += 67108864;
    _Float16* Wdh  = (_Float16*)(ws + off); off += 1048576;
    _Float16* Wihh = (_Float16*)(ws + off); off += 2097152;
    _Float16* Whhh = (_Float16*)(ws + off); off += 2097152;
    float*    wq2  = (float*)   (ws + off); off += 524288;
    float*    sA   = (float*)   (ws + off); off += 524288;
    float*    sB   = (float*)   (ws + off); off += 524288;
    _Float16* dhA  = (_Float16*)(ws + off); off += 262144;
    _Float16* dhB  = (_Float16*)(ws + off); off += 262144;
    _Float16* shA  = (_Float16*)(ws + off); off += 262144;
    _Float16* shB  = (_Float16*)(ws + off); off += 262144;
    _Float16* chb  = (_Float16*)(ws + off); off += 262144;
    _Float16* Hh   = nullptr;
    if (ws_size >= off + 67108864) { Hh = (_Float16*)(ws + off); off += 67108864; }

    convert_f16<<<512,  256, 0, stream>>>(Wd,  Wdh,  524288);
    convert_f16<<<1024, 256, 0, stream>>>(Wih, Wihh, 1048576);
    convert_f16<<<1024, 256, 0, stream>>>(Whh, Whhh, 1048576);
    if (Hh) convert_f16<<<32768, 256, 0, stream>>>(H, Hh, 33554432);
    init_state<<<512, 256, 0, stream>>>(d0, s0, sA, dhA, shA);
    uh_gemm<<<dim3(1024, 8), 256, 0, stream>>>(H, Ud, UH2);

    for (int t = 0; t < 256; t++) {
        const _Float16* dhc = (t & 1) ? dhB : dhA;
        const _Float16* shc = (t & 1) ? shB : shA;
        const float*    sc  = (t & 1) ? sB  : sA;
        _Float16* dhn = (t & 1) ? dhA : dhB;
        _Float16* shn = (t & 1) ? shA : shB;
        float*    sn  = (t & 1) ? sA  : sB;
        wq_kernel<<<dim3(32, 8), 1024, 0, stream>>>(dhc, shc, Wdh, wq2);
        attn_kernel<<<256, 1024, 0, stream>>>(UH2, Hh, H, wq2, vd, chb, attn, out, t);
        gates_kernel<<<dim3(32, 8), 1024, 0, stream>>>(chb, dhc, sc, Wihh, Whhh, bih, bhh, sn, dhn, shn, out, t);
    }
}

// Round 4
// 14667.566 us; speedup vs baseline: 6.1163x; 3.2658x over previous
//
#include <hip/hip_runtime.h>
#include <hip/hip_fp16.h>

// Problem constants: B=256, T=256, M=512, P=512
typedef _Float16 h4 __attribute__((ext_vector_type(4)));
typedef _Float16 h8 __attribute__((ext_vector_type(8)));
typedef float    f4 __attribute__((ext_vector_type(4)));

#define SC2LOG2E 2.8853900817779268f   // 2 * log2(e)

// native exp2 / rcp (v_exp_f32 IS exp2)
__device__ __forceinline__ float v_exp2(float x) { float r; asm("v_exp_f32 %0, %1" : "=v"(r) : "v"(x)); return r; }
__device__ __forceinline__ float v_rcp (float x) { float r; asm("v_rcp_f32 %0, %1" : "=v"(r) : "v"(x)); return r; }
__device__ __forceinline__ float fast_tanh(float x) {
    float e = __expf(2.0f * x);
    return 1.0f - 2.0f * v_rcp(e + 1.0f);
}
__device__ __forceinline__ float fast_sigmoid(float x) {
    return v_rcp(1.0f + __expf(-x));
}

// ---------------------------------------------------------------------------
__global__ void convert_f16(const float* __restrict__ s, _Float16* __restrict__ d, int n) {
    int i = (blockIdx.x * 256 + threadIdx.x) * 4;
    if (i < n) {
        float4 v = *(const float4*)(s + i);
        h4 o = {(_Float16)v.x, (_Float16)v.y, (_Float16)v.z, (_Float16)v.w};
        *(h4*)(d + i) = o;
    }
}

// ---------------------------------------------------------------------------
// Wg[(p<<2)|g][k] = f16( k<512 ? Wih[g*512+p][k] : Whh[g*512+p][k-512] )
__global__ void build_wg(const float* __restrict__ Wih, const float* __restrict__ Whh,
                         _Float16* __restrict__ Wg) {
    int idx = (blockIdx.x * 256 + threadIdx.x) * 4;    // over 2048*1024
    int np = idx >> 10, k = idx & 1023;
    int p = np >> 2, g = np & 3, row = g * 512 + p;
    const float* src = (k < 512) ? Wih + (size_t)row * 512 + k
                                 : Whh + (size_t)row * 512 + (k - 512);
    float4 v = *(const float4*)src;
    h4 o = {(_Float16)v.x, (_Float16)v.y, (_Float16)v.z, (_Float16)v.w};
    *(h4*)(Wg + idx) = o;
}

__global__ void build_bsum(const float* __restrict__ bih, const float* __restrict__ bhh,
                           float* __restrict__ bsum) {
    int np = blockIdx.x * 256 + threadIdx.x;  // 2048
    int p = np >> 2, g = np & 3, row = g * 512 + p;
    bsum[np] = bih[row] + bhh[row];
}

// ---------------------------------------------------------------------------
__global__ void init_state(const float* __restrict__ d0, const float* __restrict__ s0,
                           float* __restrict__ sbuf,
                           _Float16* __restrict__ qA, _Float16* __restrict__ ds) {
    int i = blockIdx.x * 256 + threadIdx.x;   // 512 x 256 = 131072
    float dv = d0[i], sv = s0[i];
    sbuf[i] = sv;
    int b = i >> 9, j = i & 511;
    qA[(size_t)b * 1024 + 512 + j] = (_Float16)dv;
    ds[(size_t)b * 1024 + j]       = (_Float16)dv;
    ds[(size_t)b * 1024 + 512 + j] = (_Float16)sv;
}

// ---------------------------------------------------------------------------
// UH2[r,n] = f16( 2log2e * sum_k H[r,k]*Ud[n,k] )  via MFMA, inline f32->f16.
// grid (1024 m-tiles of 64, 16 n-tiles of 32), 128 threads (2 waves).
__global__ __launch_bounds__(128) void uh_mfma(const float* __restrict__ H,
                                               const float* __restrict__ Ud,
                                               _Float16* __restrict__ UH2) {
    int tid = threadIdx.x;
    int lane = tid & 63, w = tid >> 6;
    int ln = lane & 15, quad = lane >> 4;
    int m0 = blockIdx.x * 64, n0 = blockIdx.y * 32;
    f4 z = {0.f, 0.f, 0.f, 0.f};
    f4 acc[4] = {z, z, z, z};
    const float* brow = Ud + (size_t)(n0 + w * 16 + ln) * 512 + quad * 8;
    const float* arow = H  + (size_t)(m0 + ln) * 512 + quad * 8;
#pragma unroll 2
    for (int k = 0; k < 16; k++) {
        float4 bx = *(const float4*)(brow + k * 32);
        float4 by = *(const float4*)(brow + k * 32 + 4);
        h8 b = {(_Float16)bx.x, (_Float16)bx.y, (_Float16)bx.z, (_Float16)bx.w,
                (_Float16)by.x, (_Float16)by.y, (_Float16)by.z, (_Float16)by.w};
#pragma unroll
        for (int mt = 0; mt < 4; mt++) {
            const float* ap = arow + (size_t)mt * 16 * 512 + k * 32;
            float4 ax = *(const float4*)ap;
            float4 ay = *(const float4*)(ap + 4);
            h8 a = {(_Float16)ax.x, (_Float16)ax.y, (_Float16)ax.z, (_Float16)ax.w,
                    (_Float16)ay.x, (_Float16)ay.y, (_Float16)ay.z, (_Float16)ay.w};
            acc[mt] = __builtin_amdgcn_mfma_f32_16x16x32_f16(a, b, acc[mt], 0, 0, 0);
        }
    }
#pragma unroll
    for (int mt = 0; mt < 4; mt++)
#pragma unroll
        for (int r = 0; r < 4; r++)
            UH2[(size_t)(m0 + mt * 16 + quad * 4 + r) * 512 + n0 + w * 16 + ln] =
                (_Float16)(acc[mt][r] * SC2LOG2E);
}

// ---------------------------------------------------------------------------
// wq2 = 2log2e * ds(256x1024) @ Wdh(512x1024)^T. grid (4,16), 128 thr, tile 64x32.
__global__ __launch_bounds__(128) void wq_gemm(const _Float16* __restrict__ ds,
                                               const _Float16* __restrict__ Wdh,
                                               float* __restrict__ wq2) {
    int tid = threadIdx.x;
    int lane = tid & 63, w = tid >> 6;
    int ln = lane & 15, quad = lane >> 4;
    int m0 = blockIdx.x * 64, n0 = blockIdx.y * 32;
    f4 z = {0.f, 0.f, 0.f, 0.f};
    f4 acc[4] = {z, z, z, z};
    const h8* bp = (const h8*)(Wdh + (size_t)(n0 + w * 16 + ln) * 1024) + quad;
    const h8* ap = (const h8*)(ds  + (size_t)(m0 + ln) * 1024) + quad;
#pragma unroll 4
    for (int k = 0; k < 32; k++) {
        h8 b  = bp[k * 4];
        h8 a0 = ap[k * 4];
        h8 a1 = ap[k * 4 + 16 * 128];
        h8 a2 = ap[k * 4 + 32 * 128];
        h8 a3 = ap[k * 4 + 48 * 128];
        acc[0] = __builtin_amdgcn_mfma_f32_16x16x32_f16(a0, b, acc[0], 0, 0, 0);
        acc[1] = __builtin_amdgcn_mfma_f32_16x16x32_f16(a1, b, acc[1], 0, 0, 0);
        acc[2] = __builtin_amdgcn_mfma_f32_16x16x32_f16(a2, b, acc[2], 0, 0, 0);
        acc[3] = __builtin_amdgcn_mfma_f32_16x16x32_f16(a3, b, acc[3], 0, 0, 0);
    }
#pragma unroll
    for (int mt = 0; mt < 4; mt++)
#pragma unroll
        for (int r = 0; r < 4; r++)
            wq2[(size_t)(m0 + mt * 16 + quad * 4 + r) * 512 + n0 + w * 16 + ln] =
                acc[mt][r] * SC2LOG2E;
}

// ---------------------------------------------------------------------------
// gates = qcur(256x1024 [c|d]) @ Wg(2048x1024)^T + bsum ; fused LSTM cell.
// grid (4 m-tiles, 64 n-tiles of 32), 128 thr. n-tile = 8 p-values x 4 gates.
__global__ __launch_bounds__(128) void gates_gemm(const _Float16* __restrict__ qcur,
                                                  const _Float16* __restrict__ Wg,
                                                  const float* __restrict__ bsum,
                                                  float* __restrict__ sbuf,
                                                  _Float16* __restrict__ qnext,
                                                  _Float16* __restrict__ ds,
                                                  float* __restrict__ out,
                                                  int t) {
    __shared__ float gt[64][36];   // padded: epilogue writes conflict-free
    int tid = threadIdx.x;
    int lane = tid & 63, w = tid >> 6;
    int ln = lane & 15, quad = lane >> 4;
    int m0 = blockIdx.x * 64, n0 = blockIdx.y * 32;
    f4 z = {0.f, 0.f, 0.f, 0.f};
    f4 acc[4] = {z, z, z, z};
    const h8* bp = (const h8*)(Wg   + (size_t)(n0 + w * 16 + ln) * 1024) + quad;
    const h8* ap = (const h8*)(qcur + (size_t)(m0 + ln) * 1024) + quad;
#pragma unroll 4
    for (int k = 0; k < 32; k++) {
        h8 b  = bp[k * 4];
        h8 a0 = ap[k * 4];
        h8 a1 = ap[k * 4 + 16 * 128];
        h8 a2 = ap[k * 4 + 32 * 128];
        h8 a3 = ap[k * 4 + 48 * 128];
        acc[0] = __builtin_amdgcn_mfma_f32_16x16x32_f16(a0, b, acc[0], 0, 0, 0);
        acc[1] = __builtin_amdgcn_mfma_f32_16x16x32_f16(a1, b, acc[1], 0, 0, 0);
        acc[2] = __builtin_amdgcn_mfma_f32_16x16x32_f16(a2, b, acc[2], 0, 0, 0);
        acc[3] = __builtin_amdgcn_mfma_f32_16x16x32_f16(a3, b, acc[3], 0, 0, 0);
    }
    float bs = bsum[n0 + w * 16 + ln];
#pragma unroll
    for (int mt = 0; mt < 4; mt++)
#pragma unroll
        for (int r = 0; r < 4; r++)
            gt[mt * 16 + quad * 4 + r][w * 16 + ln] = acc[mt][r] + bs;
    __syncthreads();

    int p0 = blockIdx.y * 8;
#pragma unroll
    for (int i = 0; i < 4; i++) {
        int idx = tid + 128 * i;          // 0..511
        int ml = idx >> 3, pl = idx & 7;
        float4 g4 = *(const float4*)&gt[ml][pl * 4];
        int b = m0 + ml, p = p0 + pl;
        float ig = fast_sigmoid(g4.x);
        float fg = fast_sigmoid(g4.y);
        float gg = fast_tanh(g4.z);
        float og = fast_sigmoid(g4.w);
        float sold = sbuf[(size_t)b * 512 + p];
        float snew = fmaf(fg, sold, ig * gg);
        float dnew = og * fast_tanh(snew);
        sbuf[(size_t)b * 512 + p] = snew;
        qnext[(size_t)b * 1024 + 512 + p] = (_Float16)dnew;
        ds[(size_t)b * 1024 + p]          = (_Float16)dnew;
        ds[(size_t)b * 1024 + 512 + p]    = (_Float16)snew;
        if (t == 255) out[(size_t)b * 1024 + p] = dnew;
    }
}

// ---------------------------------------------------------------------------
// Per-b attention. grid 256 (block per b), 1024 threads (16 waves).
__global__ __launch_bounds__(1024) void attn_kernel(const _Float16* __restrict__ UH2,
                                                    const _Float16* __restrict__ Hh,
                                                    const float* __restrict__ Hf,
                                                    const float* __restrict__ wq2,
                                                    const float* __restrict__ vd,
                                                    _Float16* __restrict__ qcur,
                                                    float* __restrict__ attn_out,
                                                    float* __restrict__ out,
                                                    int t) {
    __shared__ float es[256];
    __shared__ float red[4];
    __shared__ float red2[4];
    __shared__ float part[8][512];

    int b = blockIdx.x;
    int tid = threadIdx.x;
    int wv = tid >> 6, lane = tid & 63;

    const float4* wqp = (const float4*)(wq2 + (size_t)b * 512 + lane * 8);
    float4 w0 = wqp[0], w1 = wqp[1];
    const float4* vp = (const float4*)(vd + lane * 8);
    float4 vv0 = vp[0], vv1 = vp[1];
    float wr[8] = {w0.x, w0.y, w0.z, w0.w, w1.x, w1.y, w1.z, w1.w};
    float vr[8] = {vv0.x, vv0.y, vv0.z, vv0.w, vv1.x, vv1.y, vv1.z, vv1.w};

    const h8* up = (const h8*)(UH2 + (size_t)b * 256 * 512) + lane;
#pragma unroll 2
    for (int i = 0; i < 16; i++) {
        int tp = wv * 16 + i;
        h8 u = up[(size_t)tp * 64];
        float acc = 0.0f;
#pragma unroll
        for (int j = 0; j < 8; j++) {
            float zz = wr[j] + (float)u[j];
            float r = v_rcp(1.0f + v_exp2(zz));
            acc = fmaf(vr[j], r, acc);
        }
#pragma unroll
        for (int o = 32; o; o >>= 1) acc += __shfl_xor(acc, o, 64);
        if (lane == 0) es[tp] = -2.0f * acc;
    }
    __syncthreads();

    float v = 0.0f, ex = 0.0f;
    if (tid < 256) {
        v = es[tid];
        float mx = v;
#pragma unroll
        for (int o = 32; o; o >>= 1) mx = fmaxf(mx, __shfl_xor(mx, o, 64));
        if (lane == 0) red[wv] = mx;
    }
    __syncthreads();
    float mall = fmaxf(fmaxf(red[0], red[1]), fmaxf(red[2], red[3]));
    if (tid < 256) {
        ex = __expf(v - mall);
        float s = ex;
#pragma unroll
        for (int o = 32; o; o >>= 1) s += __shfl_xor(s, o, 64);
        if (lane == 0) red2[wv] = s;
    }
    __syncthreads();
    float tot = red2[0] + red2[1] + red2[2] + red2[3];
    float beta = 0.0f;
    if (tid < 256) beta = ex * v_rcp(tot);
    __syncthreads();
    if (tid < 256) {
        es[tid] = beta;
        attn_out[(size_t)b * 65536 + (size_t)t * 256 + tid] = beta;
    }
    __syncthreads();

    // c phase
    int tc = tid >> 7, g = tid & 127;
    float a0 = 0, a1 = 0, a2 = 0, a3 = 0;
    if (Hh) {
        const h4* hp = (const h4*)(Hh + ((size_t)b * 256 + tc * 32) * 512) + g;
#pragma unroll 4
        for (int i = 0; i < 32; i++) {
            h4 hv = hp[(size_t)i * 128];
            float bt = es[tc * 32 + i];
            a0 = fmaf(bt, (float)hv[0], a0);
            a1 = fmaf(bt, (float)hv[1], a1);
            a2 = fmaf(bt, (float)hv[2], a2);
            a3 = fmaf(bt, (float)hv[3], a3);
        }
    } else {
        const float4* hp = (const float4*)(Hf + ((size_t)b * 256 + tc * 32) * 512) + g;
#pragma unroll 4
        for (int i = 0; i < 32; i++) {
            float4 hv = hp[(size_t)i * 128];
            float bt = es[tc * 32 + i];
            a0 = fmaf(bt, hv.x, a0);
            a1 = fmaf(bt, hv.y, a1);
            a2 = fmaf(bt, hv.z, a2);
            a3 = fmaf(bt, hv.w, a3);
        }
    }
    *(float4*)&part[tc][g * 4] = make_float4(a0, a1, a2, a3);
    __syncthreads();
    if (tid < 512) {
        int m = tid;
        float c = part[0][m] + part[1][m] + part[2][m] + part[3][m]
                + part[4][m] + part[5][m] + part[6][m] + part[7][m];
        qcur[(size_t)b * 1024 + m] = (_Float16)c;
        if (t == 255) out[(size_t)b * 1024 + 512 + m] = c;
    }
}

// ---------------------------------------------------------------------------
extern "C" void kernel_launch(void* const* d_in, const int* in_sizes, int n_in,
                              void* d_out, int out_size, void* d_ws, size_t ws_size,
                              hipStream_t stream) {
    const float* H   = (const float*)d_in[0];
    const float* d0  = (const float*)d_in[1];
    const float* s0  = (const float*)d_in[2];
    const float* Wd  = (const float*)d_in[3];
    const float* Ud  = (const float*)d_in[4];
    const float* vd  = (const float*)d_in[5];
    const float* Wih = (const float*)d_in[6];
    const float* Whh = (const float*)d_in[7];
    const float* bih = (const float*)d_in[8];
    const float* bhh = (const float*)d_in[9];

    float* out  = (float*)d_out;            // [B,1,1024]
    float* attn = out + 262144;             // [B,T,T]

    char* ws = (char*)d_ws;
    size_t off = 0;
    _Float16* UH2  = (_Float16*)(ws + off); off += 67108864;
    _Float16* Wdh  = (_Float16*)(ws + off); off += 1048576;
    _Float16* Wg   = (_Float16*)(ws + off); off += 4194304;
    float*    bsum = (float*)   (ws + off); off += 8192;
    float*    wq2  = (float*)   (ws + off); off += 524288;
    _Float16* qA   = (_Float16*)(ws + off); off += 524288;
    _Float16* qB   = (_Float16*)(ws + off); off += 524288;
    _Float16* ds   = (_Float16*)(ws + off); off += 524288;
    float*    sbuf = (float*)   (ws + off); off += 524288;
    _Float16* Hh   = nullptr;
    if (ws_size >= off + 67108864) { Hh = (_Float16*)(ws + off); off += 67108864; }

    convert_f16<<<512, 256, 0, stream>>>(Wd, Wdh, 524288);
    build_wg<<<2048, 256, 0, stream>>>(Wih, Whh, Wg);
    build_bsum<<<8, 256, 0, stream>>>(bih, bhh, bsum);
    if (Hh) convert_f16<<<32768, 256, 0, stream>>>(H, Hh, 33554432);
    init_state<<<512, 256, 0, stream>>>(d0, s0, sbuf, qA, ds);
    uh_mfma<<<dim3(1024, 16), 128, 0, stream>>>(H, Ud, UH2);

    for (int t = 0; t < 256; t++) {
        _Float16* qcur = (t & 1) ? qB : qA;
        _Float16* qnxt = (t & 1) ? qA : qB;
        wq_gemm<<<dim3(4, 16), 128, 0, stream>>>(ds, Wdh, wq2);
        attn_kernel<<<256, 1024, 0, stream>>>(UH2, Hh, H, wq2, vd, qcur, attn, out, t);
        gates_gemm<<<dim3(4, 64), 128, 0, stream>>>(qcur, Wg, bsum, sbuf, qnxt, ds, out, t);
    }
}

// Round 5
// 14357.741 us; speedup vs baseline: 6.2483x; 1.0216x over previous
//
#include <hip/hip_runtime.h>
#include <hip/hip_fp16.h>

// Problem constants: B=256, T=256, M=512, P=512
typedef _Float16 h4 __attribute__((ext_vector_type(4)));
typedef _Float16 h8 __attribute__((ext_vector_type(8)));
typedef float    f4 __attribute__((ext_vector_type(4)));

#define SC2LOG2E 2.8853900817779268f   // 2 * log2(e)

// native exp2 / rcp (v_exp_f32 IS exp2)
__device__ __forceinline__ float v_exp2(float x) { float r; asm("v_exp_f32 %0, %1" : "=v"(r) : "v"(x)); return r; }
__device__ __forceinline__ float v_rcp (float x) { float r; asm("v_rcp_f32 %0, %1" : "=v"(r) : "v"(x)); return r; }
__device__ __forceinline__ float fast_tanh(float x) {
    float e = __expf(2.0f * x);
    return 1.0f - 2.0f * v_rcp(e + 1.0f);
}
__device__ __forceinline__ float fast_sigmoid(float x) {
    return v_rcp(1.0f + __expf(-x));
}

// ---------------------------------------------------------------------------
__global__ void convert_f16(const float* __restrict__ s, _Float16* __restrict__ d, int n) {
    int i = (blockIdx.x * 256 + threadIdx.x) * 4;
    if (i < n) {
        float4 v = *(const float4*)(s + i);
        h4 o = {(_Float16)v.x, (_Float16)v.y, (_Float16)v.z, (_Float16)v.w};
        *(h4*)(d + i) = o;
    }
}

// ---------------------------------------------------------------------------
// Wg[(p<<2)|g][k] = f16( k<512 ? Wih[g*512+p][k] : Whh[g*512+p][k-512] )
__global__ void build_wg(const float* __restrict__ Wih, const float* __restrict__ Whh,
                         _Float16* __restrict__ Wg) {
    int idx = (blockIdx.x * 256 + threadIdx.x) * 4;    // over 2048*1024
    int np = idx >> 10, k = idx & 1023;
    int p = np >> 2, g = np & 3, row = g * 512 + p;
    const float* src = (k < 512) ? Wih + (size_t)row * 512 + k
                                 : Whh + (size_t)row * 512 + (k - 512);
    float4 v = *(const float4*)src;
    h4 o = {(_Float16)v.x, (_Float16)v.y, (_Float16)v.z, (_Float16)v.w};
    *(h4*)(Wg + idx) = o;
}

__global__ void build_bsum(const float* __restrict__ bih, const float* __restrict__ bhh,
                           float* __restrict__ bsum) {
    int np = blockIdx.x * 256 + threadIdx.x;  // 2048
    int p = np >> 2, g = np & 3, row = g * 512 + p;
    bsum[np] = bih[row] + bhh[row];
}

// ---------------------------------------------------------------------------
__global__ void init_state(const float* __restrict__ d0, const float* __restrict__ s0,
                           float* __restrict__ sbuf,
                           _Float16* __restrict__ qA, _Float16* __restrict__ ds) {
    int i = blockIdx.x * 256 + threadIdx.x;   // 512 x 256 = 131072
    float dv = d0[i], sv = s0[i];
    sbuf[i] = sv;
    int b = i >> 9, j = i & 511;
    qA[(size_t)b * 1024 + 512 + j] = (_Float16)dv;
    ds[(size_t)b * 1024 + j]       = (_Float16)dv;
    ds[(size_t)b * 1024 + 512 + j] = (_Float16)sv;
}

// ---------------------------------------------------------------------------
// UH2[r,n] = f16( 2log2e * sum_k H[r,k]*Ud[n,k] )  via MFMA, inline f32->f16.
// grid (1024 m-tiles of 64, 16 n-tiles of 32), 128 threads (2 waves).
__global__ __launch_bounds__(128) void uh_mfma(const float* __restrict__ H,
                                               const float* __restrict__ Ud,
                                               _Float16* __restrict__ UH2) {
    int tid = threadIdx.x;
    int lane = tid & 63, w = tid >> 6;
    int ln = lane & 15, quad = lane >> 4;
    int m0 = blockIdx.x * 64, n0 = blockIdx.y * 32;
    f4 z = {0.f, 0.f, 0.f, 0.f};
    f4 acc[4] = {z, z, z, z};
    const float* brow = Ud + (size_t)(n0 + w * 16 + ln) * 512 + quad * 8;
    const float* arow = H  + (size_t)(m0 + ln) * 512 + quad * 8;
#pragma unroll 2
    for (int k = 0; k < 16; k++) {
        float4 bx = *(const float4*)(brow + k * 32);
        float4 by = *(const float4*)(brow + k * 32 + 4);
        h8 b = {(_Float16)bx.x, (_Float16)bx.y, (_Float16)bx.z, (_Float16)bx.w,
                (_Float16)by.x, (_Float16)by.y, (_Float16)by.z, (_Float16)by.w};
#pragma unroll
        for (int mt = 0; mt < 4; mt++) {
            const float* ap = arow + (size_t)mt * 16 * 512 + k * 32;
            float4 ax = *(const float4*)ap;
            float4 ay = *(const float4*)(ap + 4);
            h8 a = {(_Float16)ax.x, (_Float16)ax.y, (_Float16)ax.z, (_Float16)ax.w,
                    (_Float16)ay.x, (_Float16)ay.y, (_Float16)ay.z, (_Float16)ay.w};
            acc[mt] = __builtin_amdgcn_mfma_f32_16x16x32_f16(a, b, acc[mt], 0, 0, 0);
        }
    }
#pragma unroll
    for (int mt = 0; mt < 4; mt++)
#pragma unroll
        for (int r = 0; r < 4; r++)
            UH2[(size_t)(m0 + mt * 16 + quad * 4 + r) * 512 + n0 + w * 16 + ln] =
                (_Float16)(acc[mt][r] * SC2LOG2E);
}

// ---------------------------------------------------------------------------
// wq2 = 2log2e * ds(256x1024) @ Wdh(512x1024)^T.
// grid (4 m-tiles of 64, 32 n-tiles of 16) = 128 blocks, 256 thr = 4 waves.
// Wave w owns the 16x16 tile (m-sub w), full K=1024.
__global__ __launch_bounds__(256) void wq_gemm(const _Float16* __restrict__ ds,
                                               const _Float16* __restrict__ Wdh,
                                               float* __restrict__ wq2) {
    int tid = threadIdx.x;
    int lane = tid & 63, w = tid >> 6;
    int ln = lane & 15, quad = lane >> 4;
    int m0 = blockIdx.x * 64, n0 = blockIdx.y * 16;
    f4 acc = {0.f, 0.f, 0.f, 0.f};
    const h8* ap = (const h8*)(ds  + (size_t)(m0 + w * 16 + ln) * 1024) + quad;
    const h8* bp = (const h8*)(Wdh + (size_t)(n0 + ln) * 1024) + quad;
#pragma unroll 8
    for (int k = 0; k < 32; k++) {
        h8 a = ap[k * 4];
        h8 b = bp[k * 4];
        acc = __builtin_amdgcn_mfma_f32_16x16x32_f16(a, b, acc, 0, 0, 0);
    }
#pragma unroll
    for (int r = 0; r < 4; r++)
        wq2[(size_t)(m0 + w * 16 + quad * 4 + r) * 512 + n0 + ln] = acc[r] * SC2LOG2E;
}

// ---------------------------------------------------------------------------
// gates = qcur(256x1024 [c|d]) @ Wg(2048x1024)^T + bsum ; fused LSTM cell.
// grid (4 m-tiles of 64, 64 n-tiles of 32) = 256 blocks, 512 thr = 8 waves.
// Wave w owns 16x16 tile: m-sub = w&3, n-sub = w>>2; full K=1024.
__global__ __launch_bounds__(512) void gates_gemm(const _Float16* __restrict__ qcur,
                                                  const _Float16* __restrict__ Wg,
                                                  const float* __restrict__ bsum,
                                                  float* __restrict__ sbuf,
                                                  _Float16* __restrict__ qnext,
                                                  _Float16* __restrict__ ds,
                                                  float* __restrict__ out,
                                                  int t) {
    __shared__ float gt[64][36];   // padded
    int tid = threadIdx.x;
    int lane = tid & 63, w = tid >> 6;
    int ln = lane & 15, quad = lane >> 4;
    int mt = w & 3, nt = w >> 2;
    int m0 = blockIdx.x * 64, n0 = blockIdx.y * 32;
    f4 acc = {0.f, 0.f, 0.f, 0.f};
    const h8* ap = (const h8*)(qcur + (size_t)(m0 + mt * 16 + ln) * 1024) + quad;
    const h8* bp = (const h8*)(Wg   + (size_t)(n0 + nt * 16 + ln) * 1024) + quad;
#pragma unroll 8
    for (int k = 0; k < 32; k++) {
        h8 a = ap[k * 4];
        h8 b = bp[k * 4];
        acc = __builtin_amdgcn_mfma_f32_16x16x32_f16(a, b, acc, 0, 0, 0);
    }
    float bs = bsum[n0 + nt * 16 + ln];
#pragma unroll
    for (int r = 0; r < 4; r++)
        gt[mt * 16 + quad * 4 + r][nt * 16 + ln] = acc[r] + bs;
    __syncthreads();

    // epilogue: one (b,p) per thread; 64 batches x 8 p = 512
    int p0 = blockIdx.y * 8;
    int ml = tid >> 3, pl = tid & 7;
    float4 g4 = *(const float4*)&gt[ml][pl * 4];
    int b = m0 + ml, p = p0 + pl;
    float ig = fast_sigmoid(g4.x);
    float fg = fast_sigmoid(g4.y);
    float gg = fast_tanh(g4.z);
    float og = fast_sigmoid(g4.w);
    float sold = sbuf[(size_t)b * 512 + p];
    float snew = fmaf(fg, sold, ig * gg);
    float dnew = og * fast_tanh(snew);
    sbuf[(size_t)b * 512 + p] = snew;
    qnext[(size_t)b * 1024 + 512 + p] = (_Float16)dnew;
    ds[(size_t)b * 1024 + p]          = (_Float16)dnew;
    ds[(size_t)b * 1024 + 512 + p]    = (_Float16)snew;
    if (t == 255) out[(size_t)b * 1024 + p] = dnew;
}

// ---------------------------------------------------------------------------
// Per-b attention. grid 256 (block per b), 1024 threads (16 waves).
__global__ __launch_bounds__(1024) void attn_kernel(const _Float16* __restrict__ UH2,
                                                    const _Float16* __restrict__ Hh,
                                                    const float* __restrict__ Hf,
                                                    const float* __restrict__ wq2,
                                                    const float* __restrict__ vd,
                                                    _Float16* __restrict__ qcur,
                                                    float* __restrict__ attn_out,
                                                    float* __restrict__ out,
                                                    int t) {
    __shared__ float es[256];
    __shared__ float red[4];
    __shared__ float red2[4];
    __shared__ float part[8][512];

    int b = blockIdx.x;
    int tid = threadIdx.x;
    int wv = tid >> 6, lane = tid & 63;

    const float4* wqp = (const float4*)(wq2 + (size_t)b * 512 + lane * 8);
    float4 w0 = wqp[0], w1 = wqp[1];
    const float4* vp = (const float4*)(vd + lane * 8);
    float4 vv0 = vp[0], vv1 = vp[1];
    float wr[8] = {w0.x, w0.y, w0.z, w0.w, w1.x, w1.y, w1.z, w1.w};
    float vr[8] = {vv0.x, vv0.y, vv0.z, vv0.w, vv1.x, vv1.y, vv1.z, vv1.w};

    const h8* up = (const h8*)(UH2 + (size_t)b * 256 * 512) + lane;
#pragma unroll 2
    for (int i = 0; i < 16; i++) {
        int tp = wv * 16 + i;
        h8 u = up[(size_t)tp * 64];
        float acc = 0.0f;
#pragma unroll
        for (int j = 0; j < 8; j++) {
            float zz = wr[j] + (float)u[j];
            float r = v_rcp(1.0f + v_exp2(zz));
            acc = fmaf(vr[j], r, acc);
        }
#pragma unroll
        for (int o = 32; o; o >>= 1) acc += __shfl_xor(acc, o, 64);
        if (lane == 0) es[tp] = -2.0f * acc;
    }
    __syncthreads();

    float v = 0.0f, ex = 0.0f;
    if (tid < 256) {
        v = es[tid];
        float mx = v;
#pragma unroll
        for (int o = 32; o; o >>= 1) mx = fmaxf(mx, __shfl_xor(mx, o, 64));
        if (lane == 0) red[wv] = mx;
    }
    __syncthreads();
    float mall = fmaxf(fmaxf(red[0], red[1]), fmaxf(red[2], red[3]));
    if (tid < 256) {
        ex = __expf(v - mall);
        float s = ex;
#pragma unroll
        for (int o = 32; o; o >>= 1) s += __shfl_xor(s, o, 64);
        if (lane == 0) red2[wv] = s;
    }
    __syncthreads();
    float tot = red2[0] + red2[1] + red2[2] + red2[3];
    float beta = 0.0f;
    if (tid < 256) beta = ex * v_rcp(tot);
    __syncthreads();
    if (tid < 256) {
        es[tid] = beta;
        attn_out[(size_t)b * 65536 + (size_t)t * 256 + tid] = beta;
    }
    __syncthreads();

    // c phase
    int tc = tid >> 7, g = tid & 127;
    float a0 = 0, a1 = 0, a2 = 0, a3 = 0;
    if (Hh) {
        const h4* hp = (const h4*)(Hh + ((size_t)b * 256 + tc * 32) * 512) + g;
#pragma unroll 4
        for (int i = 0; i < 32; i++) {
            h4 hv = hp[(size_t)i * 128];
            float bt = es[tc * 32 + i];
            a0 = fmaf(bt, (float)hv[0], a0);
            a1 = fmaf(bt, (float)hv[1], a1);
            a2 = fmaf(bt, (float)hv[2], a2);
            a3 = fmaf(bt, (float)hv[3], a3);
        }
    } else {
        const float4* hp = (const float4*)(Hf + ((size_t)b * 256 + tc * 32) * 512) + g;
#pragma unroll 4
        for (int i = 0; i < 32; i++) {
            float4 hv = hp[(size_t)i * 128];
            float bt = es[tc * 32 + i];
            a0 = fmaf(bt, hv.x, a0);
            a1 = fmaf(bt, hv.y, a1);
            a2 = fmaf(bt, hv.z, a2);
            a3 = fmaf(bt, hv.w, a3);
        }
    }
    *(float4*)&part[tc][g * 4] = make_float4(a0, a1, a2, a3);
    __syncthreads();
    if (tid < 512) {
        int m = tid;
        float c = part[0][m] + part[1][m] + part[2][m] + part[3][m]
                + part[4][m] + part[5][m] + part[6][m] + part[7][m];
        qcur[(size_t)b * 1024 + m] = (_Float16)c;
        if (t == 255) out[(size_t)b * 1024 + 512 + m] = c;
    }
}

// ---------------------------------------------------------------------------
extern "C" void kernel_launch(void* const* d_in, const int* in_sizes, int n_in,
                              void* d_out, int out_size, void* d_ws, size_t ws_size,
                              hipStream_t stream) {
    const float* H   = (const float*)d_in[0];
    const float* d0  = (const float*)d_in[1];
    const float* s0  = (const float*)d_in[2];
    const float* Wd  = (const float*)d_in[3];
    const float* Ud  = (const float*)d_in[4];
    const float* vd  = (const float*)d_in[5];
    const float* Wih = (const float*)d_in[6];
    const float* Whh = (const float*)d_in[7];
    const float* bih = (const float*)d_in[8];
    const float* bhh = (const float*)d_in[9];

    float* out  = (float*)d_out;            // [B,1,1024]
    float* attn = out + 262144;             // [B,T,T]

    char* ws = (char*)d_ws;
    size_t off = 0;
    _Float16* UH2  = (_Float16*)(ws + off); off += 67108864;
    _Float16* Wdh  = (_Float16*)(ws + off); off += 1048576;
    _Float16* Wg   = (_Float16*)(ws + off); off += 4194304;
    float*    bsum = (float*)   (ws + off); off += 8192;
    float*    wq2  = (float*)   (ws + off); off += 524288;
    _Float16* qA   = (_Float16*)(ws + off); off += 524288;
    _Float16* qB   = (_Float16*)(ws + off); off += 524288;
    _Float16* ds   = (_Float16*)(ws + off); off += 524288;
    float*    sbuf = (float*)   (ws + off); off += 524288;
    _Float16* Hh   = nullptr;
    if (ws_size >= off + 67108864) { Hh = (_Float16*)(ws + off); off += 67108864; }

    convert_f16<<<512, 256, 0, stream>>>(Wd, Wdh, 524288);
    build_wg<<<2048, 256, 0, stream>>>(Wih, Whh, Wg);
    build_bsum<<<8, 256, 0, stream>>>(bih, bhh, bsum);
    if (Hh) convert_f16<<<32768, 256, 0, stream>>>(H, Hh, 33554432);
    init_state<<<512, 256, 0, stream>>>(d0, s0, sbuf, qA, ds);
    uh_mfma<<<dim3(1024, 16), 128, 0, stream>>>(H, Ud, UH2);

    for (int t = 0; t < 256; t++) {
        _Float16* qcur = (t & 1) ? qB : qA;
        _Float16* qnxt = (t & 1) ? qA : qB;
        wq_gemm<<<dim3(4, 32), 256, 0, stream>>>(ds, Wdh, wq2);
        attn_kernel<<<256, 1024, 0, stream>>>(UH2, Hh, H, wq2, vd, qcur, attn, out, t);
        gates_gemm<<<dim3(4, 64), 512, 0, stream>>>(qcur, Wg, bsum, sbuf, qnxt, ds, out, t);
    }
}